// Round 1
// baseline (346.492 us; speedup 1.0000x reference)
//
#include <hip/hip_runtime.h>

// Loss kernel: out[v, 0:4] = (bx,by,bw,bh) scalars, out[v,4] = 0, out[v,5:] = y[v,5:]
// N=500000, D=85, f32. Memory-bound: ~170MB read + ~170MB write -> ~54us roofline.

#define D_COLS 85
#define AC_CONST 1e-16f

__global__ __launch_bounds__(256) void loss_kernel(const float* __restrict__ x,
                                                   const float* __restrict__ y,
                                                   float* __restrict__ out,
                                                   int n4 /* number of float4 elements */) {
    // Head scalars: computed redundantly per-thread (broadcast loads, cached; trivial ALU).
    const float px = x[0];
    const float py = x[1];
    const float tx = y[0];
    const float ty = y[1];
    const float bx = 1.0f / (1.0f + expf(-px)) + tx;   // sigmoid(px) + tx
    const float by = 1.0f / (1.0f + expf(-py)) + ty;   // sigmoid(py) + ty
    const float bw = AC_CONST * expf(px);              // replicates source's use of px
    const float bh = AC_CONST * expf(py);              // replicates source's use of py

    const float4* __restrict__ y4 = reinterpret_cast<const float4*>(y);
    float4* __restrict__ o4 = reinterpret_cast<float4*>(out);

    const int stride = gridDim.x * blockDim.x;
    for (int i = blockIdx.x * blockDim.x + threadIdx.x; i < n4; i += stride) {
        float4 v = y4[i];

        const int f = i * 4;              // flat element index of v.x (fits in int: 42.5M)
        const int row = f / D_COLS;       // constant divisor -> magic multiply
        int c0 = f - row * D_COLS;        // column of v.x, in [0,85)

        float r[4] = {v.x, v.y, v.z, v.w};
        #pragma unroll
        for (int j = 0; j < 4; ++j) {
            int c = c0 + j;
            if (c >= D_COLS) c -= D_COLS; // float4 may straddle a row boundary
            if (c < 5) {
                r[j] = (c == 0) ? bx
                     : (c == 1) ? by
                     : (c == 2) ? bw
                     : (c == 3) ? bh
                     : 0.0f;              // c == 4: objectness column zeroed
            }
        }
        o4[i] = make_float4(r[0], r[1], r[2], r[3]);
    }
}

extern "C" void kernel_launch(void* const* d_in, const int* in_sizes, int n_in,
                              void* d_out, int out_size, void* d_ws, size_t ws_size,
                              hipStream_t stream) {
    const float* x = (const float*)d_in[0];
    const float* y = (const float*)d_in[1];
    float* out = (float*)d_out;

    const int total = out_size;          // 500000 * 85 = 42,500,000 (divisible by 4)
    const int n4 = total / 4;            // 10,625,000 float4s, no tail

    const int block = 256;
    int grid = (n4 + block - 1) / block;
    const int max_grid = 256 * 8;        // 256 CUs x 8 blocks/CU; grid-stride the rest
    if (grid > max_grid) grid = max_grid;

    loss_kernel<<<grid, block, 0, stream>>>(x, y, out, n4);
}